// Round 8
// baseline (1456.062 us; speedup 1.0000x reference)
//
#include <hip/hip_runtime.h>

#define T_TOK 16384
#define H_DIM 2048
#define I_DIM 1024
#define E_NUM 8

// ---- workspace layout (bytes) ----
static const size_t F_WGT = 0;              // wgT [e][I][H] f16, 33554432
static const size_t F_WUT = 33554432ull;    // wuT [e][I][H] f16
static const size_t F_XH  = 67108864ull;    // xh  [T][H] f16, 67108864
static const size_t F_Y2  = 0;              // y2 [32768][H] f16 (overlays wgT/wuT/xh after gemm1)
static const size_t F_WDT = 134217728ull;   // wdT [e][H][I] f16, 33554432
static const size_t F_HDN = 167772160ull;   // hdn [32768][I] f16, 67108864
static const size_t F_TOK = 234881024ull;   // tok_list [E][T] int
static const size_t F_WT  = 235405312ull;   // wt_list  [E][T] f32
static const size_t F_IDX = 235929600ull;   // idx2 [T][2] int (e<<16|pos)
static const size_t F_CNT = 236060672ull;   // counts

typedef float f32x4 __attribute__((ext_vector_type(4)));
typedef _Float16 f16x8 __attribute__((ext_vector_type(8)));
typedef _Float16 f16x4 __attribute__((ext_vector_type(4)));

__device__ __forceinline__ void gload_lds16(const void* g, void* l) {
  __builtin_amdgcn_global_load_lds(
      (const __attribute__((address_space(1))) unsigned int*)g,
      (__attribute__((address_space(3))) unsigned int*)l, 16, 0, 0);
}

// ---------------------------------------------------------------------------
// K0: weight transpose + f32->f16 convert.  in [R][C] f32 -> out [C][R] f16
// ---------------------------------------------------------------------------
__global__ __launch_bounds__(256) void wconv_kernel(
    const float* __restrict__ wg, const float* __restrict__ wu,
    const float* __restrict__ wd, _Float16* __restrict__ wgT,
    _Float16* __restrict__ wuT, _Float16* __restrict__ wdT) {
  const int bx = blockIdx.x;
  const int w = bx >> 12;
  const int r2 = bx & 4095;
  const int e = r2 >> 9;
  const int t = r2 & 511;

  const float* src;
  _Float16* dst;
  int R, C;
  if (w == 0)      { src = wg; dst = wgT; R = H_DIM; C = I_DIM; }
  else if (w == 1) { src = wu; dst = wuT; R = H_DIM; C = I_DIM; }
  else             { src = wd; dst = wdT; R = I_DIM; C = H_DIM; }
  src += (size_t)e * R * C;
  dst += (size_t)e * R * C;

  const int tiles_c = C >> 6;
  const int tr = t / tiles_c;
  const int tc = t % tiles_c;

  __shared__ float tile[64][65];
  const int tid = threadIdx.x;

#pragma unroll
  for (int c = 0; c < 4; ++c) {
    const int q = c * 256 + tid;
    const int row = q >> 4;
    const int col4 = (q & 15) * 4;
    const float4 v = *(const float4*)(src + (size_t)(tr * 64 + row) * C + tc * 64 + col4);
    tile[row][col4 + 0] = v.x;
    tile[row][col4 + 1] = v.y;
    tile[row][col4 + 2] = v.z;
    tile[row][col4 + 3] = v.w;
  }
  __syncthreads();
#pragma unroll
  for (int c = 0; c < 4; ++c) {
    const int q = c * 256 + tid;
    const int row = q >> 4;
    const int col4 = (q & 15) * 4;
    f16x4 o = { (_Float16)tile[col4 + 0][row], (_Float16)tile[col4 + 1][row],
                (_Float16)tile[col4 + 2][row], (_Float16)tile[col4 + 3][row] };
    *(f16x4*)(dst + (size_t)(tc * 64 + row) * R + tr * 64 + col4) = o;
  }
}

// ---------------------------------------------------------------------------
// K1: router.  one wave per token: logits -> out1, top-2 -> expert lists,
// and emits xh (f16 copy of x) since the row is already in registers.
// ---------------------------------------------------------------------------
__global__ __launch_bounds__(256) void router_kernel(
    const float* __restrict__ x, const float* __restrict__ gw,
    float* __restrict__ logits, int* __restrict__ tok_list,
    float* __restrict__ wt_list, int* __restrict__ idx2,
    int* __restrict__ counts, _Float16* __restrict__ xh) {
  const int lane = threadIdx.x & 63;
  const int wave = threadIdx.x >> 6;
  const int t = blockIdx.x * 4 + wave;
  const float* xr = x + (size_t)t * H_DIM;

  float xv[32];
#pragma unroll
  for (int j = 0; j < 32; ++j) xv[j] = xr[lane + j * 64];

  _Float16* xhr = xh + (size_t)t * H_DIM;
#pragma unroll
  for (int j = 0; j < 32; ++j) xhr[lane + j * 64] = (_Float16)xv[j];

  float lg[E_NUM];
#pragma unroll
  for (int e = 0; e < E_NUM; ++e) {
    const float* gr = gw + e * H_DIM;
    float s = 0.f;
#pragma unroll
    for (int j = 0; j < 32; ++j) s += xv[j] * gr[lane + j * 64];
#pragma unroll
    for (int off = 32; off > 0; off >>= 1) s += __shfl_xor(s, off, 64);
    lg[e] = s;
  }

  if (lane == 0) {
#pragma unroll
    for (int e = 0; e < E_NUM; ++e) logits[(size_t)t * E_NUM + e] = lg[e];
    float mx = lg[0];
#pragma unroll
    for (int e = 1; e < E_NUM; ++e) mx = fmaxf(mx, lg[e]);
    float se = 0.f;
#pragma unroll
    for (int e = 0; e < E_NUM; ++e) se += expf(lg[e] - mx);
    int i1 = 0; float b1 = lg[0];
#pragma unroll
    for (int e = 1; e < E_NUM; ++e) { if (lg[e] > b1) { b1 = lg[e]; i1 = e; } }
    int i2 = -1; float b2 = -1e30f;
#pragma unroll
    for (int e = 0; e < E_NUM; ++e) { if (e != i1 && lg[e] > b2) { b2 = lg[e]; i2 = e; } }
    const float p1 = expf(b1 - mx) / se;
    const float p2 = expf(b2 - mx) / se;
    int pos = atomicAdd(&counts[i1], 1);
    tok_list[i1 * T_TOK + pos] = t;
    wt_list[i1 * T_TOK + pos] = p1;
    idx2[t * 2] = (i1 << 16) | pos;
    pos = atomicAdd(&counts[i2], 1);
    tok_list[i2 * T_TOK + pos] = t;
    wt_list[i2 * T_TOK + pos] = p2;
    idx2[t * 2 + 1] = (i2 << 16) | pos;
  }
}

// ---------------------------------------------------------------------------
// K2: grouped GEMM1 (gate+up fused) + SiLU*mul -> hdn.
// 128x128 tile, BK=32, double-buffered 2-phase prefetch + XCD swizzle.
// This round: sub-phase split {stage A+Bg; gate MFMAs}{stage Bu; up MFMAs}
// with s_setprio(1) around each MFMA cluster (T5; single barrier unchanged).
// ---------------------------------------------------------------------------
__global__ __launch_bounds__(256) void gemm1_kernel(
    const _Float16* __restrict__ xh, const _Float16* __restrict__ wgT,
    const _Float16* __restrict__ wuT, const int* __restrict__ tok_list,
    const int* __restrict__ counts, _Float16* __restrict__ hdn) {
  const int cpx = (E_NUM * 128 * 8) >> 3;
  int bx = blockIdx.x;
  bx = (bx & 7) * cpx + (bx >> 3);

  const int cb = bx & 7;           // I col block
  const int rb = (bx >> 3) & 127;  // row block (worst case)
  const int e = bx >> 10;
  const int n_e = counts[e];
  const int row0 = rb * 128;
  if (row0 >= n_e) return;
  int goff = 0;
#pragma unroll
  for (int j = 0; j < E_NUM; ++j) goff += (j < e) ? counts[j] : 0;
  const int rem = min(128, n_e - row0);

  __shared__ int toks[128];
  __shared__ __attribute__((aligned(16))) _Float16 As[2][128 * 32];
  __shared__ __attribute__((aligned(16))) _Float16 Bg[2][128 * 32];
  __shared__ __attribute__((aligned(16))) _Float16 Bu[2][128 * 32];

  const int tid = threadIdx.x;
  if (tid < 128) {
    int idx = row0 + tid;
    if (idx > n_e - 1) idx = n_e - 1;
    toks[tid] = tok_list[e * T_TOK + idx];
  }
  __syncthreads();

  const int lane = tid & 63;
  const int wid = tid >> 6;
  const int wr = (wid >> 1) * 64;
  const int wcl = (wid & 1) * 64;
  const int n0 = cb * 128;

  const _Float16* wgTe = wgT + ((size_t)e * I_DIM + n0) * H_DIM;
  const _Float16* wuTe = wuT + ((size_t)e * I_DIM + n0) * H_DIM;

  const _Float16* asrc[2];
  int bofs[2], dofs[2];
#pragma unroll
  for (int c = 0; c < 2; ++c) {
    const int q = c * 256 + tid;
    const int rr = q >> 2;
    const int ch = q & 3;
    const int sch = ch ^ ((rr >> 1) & 3);   // pre-swizzled global source
    asrc[c] = xh + (size_t)toks[rr] * H_DIM + sch * 8;
    bofs[c] = rr * H_DIM + sch * 8;
    dofs[c] = q * 8;                        // linear LDS dest
  }

  const f32x4 z4 = {0.f, 0.f, 0.f, 0.f};
  f32x4 accg[4][4], accu[4][4];
#pragma unroll
  for (int m = 0; m < 4; ++m)
#pragma unroll
    for (int n = 0; n < 4; ++n) { accg[m][n] = z4; accu[m][n] = z4; }

  const int cl = lane & 15;
  const int kq = lane >> 4;

  int aoff[4], boffr[4];
#pragma unroll
  for (int m = 0; m < 4; ++m) {
    const int row = wr + m * 16 + cl;
    aoff[m] = row * 32 + ((kq ^ ((row >> 1) & 3)) * 8);
  }
#pragma unroll
  for (int n = 0; n < 4; ++n) {
    const int row = wcl + n * 16 + cl;
    boffr[n] = row * 32 + ((kq ^ ((row >> 1) & 3)) * 8);
  }

  // prologue: stage k=0 into buf 0, drain, barrier
#pragma unroll
  for (int c = 0; c < 2; ++c) {
    gload_lds16(asrc[c], &As[0][0] + dofs[c]);
    gload_lds16(wgTe + bofs[c], &Bg[0][0] + dofs[c]);
    gload_lds16(wuTe + bofs[c], &Bu[0][0] + dofs[c]);
  }
  asm volatile("s_waitcnt vmcnt(0)" ::: "memory");
  __builtin_amdgcn_s_barrier();
  __builtin_amdgcn_sched_barrier(0);

  const int NK = H_DIM / 32;
  for (int t = 0; t < NK; ++t) {
    const int cur = t & 1;
    const _Float16* Ac = &As[cur][0];
    const _Float16* Gc = &Bg[cur][0];
    const _Float16* Uc = &Bu[cur][0];
    // ---- sub-phase 1: stage A+Bg(t+1); gate MFMAs ----
    if (t + 1 < NK) {
      const int kn = (t + 1) * 32;
#pragma unroll
      for (int c = 0; c < 2; ++c) {
        gload_lds16(asrc[c] + kn, &As[cur ^ 1][0] + dofs[c]);
        gload_lds16(wgTe + bofs[c] + kn, &Bg[cur ^ 1][0] + dofs[c]);
      }
    }
    f16x8 af[4], bg[4], bu[4];
#pragma unroll
    for (int m = 0; m < 4; ++m) af[m] = *(const f16x8*)(Ac + aoff[m]);
#pragma unroll
    for (int n = 0; n < 4; ++n) bg[n] = *(const f16x8*)(Gc + boffr[n]);
    __builtin_amdgcn_s_setprio(1);
#pragma unroll
    for (int m = 0; m < 4; ++m)
#pragma unroll
      for (int n = 0; n < 4; ++n)
        accg[m][n] = __builtin_amdgcn_mfma_f32_16x16x32_f16(af[m], bg[n], accg[m][n], 0, 0, 0);
    __builtin_amdgcn_s_setprio(0);
    // ---- sub-phase 2: stage Bu(t+1); up MFMAs ----
    if (t + 1 < NK) {
      const int kn = (t + 1) * 32;
#pragma unroll
      for (int c = 0; c < 2; ++c)
        gload_lds16(wuTe + bofs[c] + kn, &Bu[cur ^ 1][0] + dofs[c]);
    }
#pragma unroll
    for (int n = 0; n < 4; ++n) bu[n] = *(const f16x8*)(Uc + boffr[n]);
    __builtin_amdgcn_s_setprio(1);
#pragma unroll
    for (int m = 0; m < 4; ++m)
#pragma unroll
      for (int n = 0; n < 4; ++n)
        accu[m][n] = __builtin_amdgcn_mfma_f32_16x16x32_f16(af[m], bu[n], accu[m][n], 0, 0, 0);
    __builtin_amdgcn_s_setprio(0);
    asm volatile("s_waitcnt vmcnt(0)" ::: "memory");
    __builtin_amdgcn_s_barrier();
    __builtin_amdgcn_sched_barrier(0);
  }

  const int rq = lane >> 4;
#pragma unroll
  for (int m = 0; m < 4; ++m) {
#pragma unroll
    for (int r = 0; r < 4; ++r) {
      const int row = wr + m * 16 + rq * 4 + r;
      if (row < rem) {
        const size_t grow = (size_t)(goff + row0 + row);
#pragma unroll
        for (int n = 0; n < 4; ++n) {
          const float g = accg[m][n][r];
          const float u = accu[m][n][r];
          const float h = g / (1.f + __expf(-g)) * u;
          hdn[grow * I_DIM + n0 + wcl + n * 16 + cl] = (_Float16)h;
        }
      }
    }
  }
}

// ---------------------------------------------------------------------------
// K3: grouped GEMM2 (down proj) -> weight-scaled compacted y2 (f16).
// NEW: 128x256 block tile (wave-tile 64x128, acc[4][8]) so the per-iter
// economics (32 MFMA / 6 gloads / barrier) match gemm1's proven shape.
// BK=32 double-buffer, swizzle, XCD swizzle, setprio cluster.
// ---------------------------------------------------------------------------
__global__ __launch_bounds__(256) void gemm2_kernel(
    const _Float16* __restrict__ hdn, const _Float16* __restrict__ wdT,
    const int* __restrict__ tok_list, const float* __restrict__ wt_list,
    const int* __restrict__ counts, _Float16* __restrict__ y2) {
  const int cpx = (E_NUM * 128 * 8) >> 3;
  int bx = blockIdx.x;
  bx = (bx & 7) * cpx + (bx >> 3);

  const int nb = bx & 7;           // H col block (256 wide)
  const int rb = (bx >> 3) & 127;  // row block of 128
  const int e = bx >> 10;
  const int n_e = counts[e];
  const int row0 = rb * 128;
  if (row0 >= n_e) return;
  int goff = 0;
#pragma unroll
  for (int j = 0; j < E_NUM; ++j) goff += (j < e) ? counts[j] : 0;
  const int rem = min(128, n_e - row0);

  __shared__ float wts[128];
  __shared__ __attribute__((aligned(16))) _Float16 As[2][128 * 32];
  __shared__ __attribute__((aligned(16))) _Float16 Bs[2][256 * 32];

  const int tid = threadIdx.x;
  if (tid < 128) {
    int idx = row0 + tid;
    const bool valid = (idx < n_e);
    wts[tid] = valid ? wt_list[e * T_TOK + min(idx, n_e - 1)] : 0.f;
  }
  __syncthreads();

  const int lane = tid & 63;
  const int wid = tid >> 6;
  const int wr = (wid >> 1) * 64;     // {0, 64}
  const int wcl = (wid & 1) * 128;    // {0, 128}
  const int h0 = nb * 256;

  const _Float16* wdTe = wdT + ((size_t)e * H_DIM + h0) * I_DIM;
  const _Float16* hdnb = hdn + (size_t)(goff + row0) * I_DIM;

  // A: 512 chunks -> 2/thread; B: 1024 chunks -> 4/thread
  const _Float16* asrc[2];
  int adofs[2];
#pragma unroll
  for (int c = 0; c < 2; ++c) {
    const int q = c * 256 + tid;
    const int rr = q >> 2;
    const int ch = q & 3;
    const int sch = ch ^ ((rr >> 1) & 3);
    const int rrc = min(rr, rem - 1);       // clamp source row only
    asrc[c] = hdnb + (size_t)rrc * I_DIM + sch * 8;
    adofs[c] = q * 8;
  }
  int bofs[4], bdofs[4];
#pragma unroll
  for (int c = 0; c < 4; ++c) {
    const int q = c * 256 + tid;
    const int rr = q >> 2;
    const int ch = q & 3;
    const int sch = ch ^ ((rr >> 1) & 3);
    bofs[c] = rr * I_DIM + sch * 8;
    bdofs[c] = q * 8;
  }

  const f32x4 z4 = {0.f, 0.f, 0.f, 0.f};
  f32x4 acc[4][8];
#pragma unroll
  for (int m = 0; m < 4; ++m)
#pragma unroll
    for (int n = 0; n < 8; ++n) acc[m][n] = z4;

  const int cl = lane & 15;
  const int kq = lane >> 4;

  int aoff[4], boffr[8];
#pragma unroll
  for (int m = 0; m < 4; ++m) {
    const int row = wr + m * 16 + cl;
    aoff[m] = row * 32 + ((kq ^ ((row >> 1) & 3)) * 8);
  }
#pragma unroll
  for (int n = 0; n < 8; ++n) {
    const int row = wcl + n * 16 + cl;
    boffr[n] = row * 32 + ((kq ^ ((row >> 1) & 3)) * 8);
  }

  // prologue
#pragma unroll
  for (int c = 0; c < 2; ++c) gload_lds16(asrc[c], &As[0][0] + adofs[c]);
#pragma unroll
  for (int c = 0; c < 4; ++c) gload_lds16(wdTe + bofs[c], &Bs[0][0] + bdofs[c]);
  asm volatile("s_waitcnt vmcnt(0)" ::: "memory");
  __builtin_amdgcn_s_barrier();
  __builtin_amdgcn_sched_barrier(0);

  const int NK = I_DIM / 32;
  for (int t = 0; t < NK; ++t) {
    const int cur = t & 1;
    if (t + 1 < NK) {
      const int kn = (t + 1) * 32;
#pragma unroll
      for (int c = 0; c < 2; ++c) gload_lds16(asrc[c] + kn, &As[cur ^ 1][0] + adofs[c]);
#pragma unroll
      for (int c = 0; c < 4; ++c) gload_lds16(wdTe + bofs[c] + kn, &Bs[cur ^ 1][0] + bdofs[c]);
    }
    const _Float16* Ac = &As[cur][0];
    const _Float16* Bc = &Bs[cur][0];
    f16x8 af[4], bf[8];
#pragma unroll
    for (int m = 0; m < 4; ++m) af[m] = *(const f16x8*)(Ac + aoff[m]);
#pragma unroll
    for (int n = 0; n < 8; ++n) bf[n] = *(const f16x8*)(Bc + boffr[n]);
    __builtin_amdgcn_s_setprio(1);
#pragma unroll
    for (int m = 0; m < 4; ++m)
#pragma unroll
      for (int n = 0; n < 8; ++n)
        acc[m][n] = __builtin_amdgcn_mfma_f32_16x16x32_f16(af[m], bf[n], acc[m][n], 0, 0, 0);
    __builtin_amdgcn_s_setprio(0);
    asm volatile("s_waitcnt vmcnt(0)" ::: "memory");
    __builtin_amdgcn_s_barrier();
    __builtin_amdgcn_sched_barrier(0);
  }

  const int rq = lane >> 4;
#pragma unroll
  for (int m = 0; m < 4; ++m) {
#pragma unroll
    for (int r = 0; r < 4; ++r) {
      const int row = wr + m * 16 + rq * 4 + r;
      if (row < rem) {
        const float w = wts[row];
        _Float16* yrow = y2 + (size_t)(goff + row0 + row) * H_DIM + h0 + wcl;
#pragma unroll
        for (int n = 0; n < 8; ++n)
          yrow[n * 16 + cl] = (_Float16)(acc[m][n][r] * w);
      }
    }
  }
}

// ---------------------------------------------------------------------------
// K4: combine — out0[t] = y2[slot0(t)] + y2[slot1(t)]
// ---------------------------------------------------------------------------
__global__ __launch_bounds__(256) void combine_kernel(
    const _Float16* __restrict__ y2, const int* __restrict__ idx2,
    const int* __restrict__ counts, float* __restrict__ out) {
  const int t = blockIdx.x;
  int pref[E_NUM];
  int run = 0;
#pragma unroll
  for (int e = 0; e < E_NUM; ++e) { pref[e] = run; run += counts[e]; }
  const int p0 = idx2[t * 2];
  const int p1 = idx2[t * 2 + 1];
  const size_t r0 = (size_t)(pref[p0 >> 16] + (p0 & 0xFFFF)) * H_DIM;
  const size_t r1 = (size_t)(pref[p1 >> 16] + (p1 & 0xFFFF)) * H_DIM;
  const int o = threadIdx.x * 8;
  const f16x8 a = *(const f16x8*)(y2 + r0 + o);
  const f16x8 b = *(const f16x8*)(y2 + r1 + o);
  float* orow = out + (size_t)t * H_DIM + o;
  float4 lo = { (float)a[0] + (float)b[0], (float)a[1] + (float)b[1],
                (float)a[2] + (float)b[2], (float)a[3] + (float)b[3] };
  float4 hi = { (float)a[4] + (float)b[4], (float)a[5] + (float)b[5],
                (float)a[6] + (float)b[6], (float)a[7] + (float)b[7] };
  *(float4*)orow = lo;
  *(float4*)(orow + 4) = hi;
}

// ---------------------------------------------------------------------------
extern "C" void kernel_launch(void* const* d_in, const int* in_sizes, int n_in,
                              void* d_out, int out_size, void* d_ws, size_t ws_size,
                              hipStream_t stream) {
  (void)in_sizes; (void)n_in; (void)out_size; (void)ws_size;
  const float* x      = (const float*)d_in[0];
  const float* gate_w = (const float*)d_in[1];
  const float* wg     = (const float*)d_in[2];
  const float* wu     = (const float*)d_in[3];
  const float* wd     = (const float*)d_in[4];
  float* out0 = (float*)d_out;
  float* out1 = out0 + (size_t)T_TOK * H_DIM;

  char* ws = (char*)d_ws;
  _Float16* wgT = (_Float16*)(ws + F_WGT);
  _Float16* wuT = (_Float16*)(ws + F_WUT);
  _Float16* xh  = (_Float16*)(ws + F_XH);
  _Float16* y2  = (_Float16*)(ws + F_Y2);
  _Float16* wdT = (_Float16*)(ws + F_WDT);
  _Float16* hdn = (_Float16*)(ws + F_HDN);
  int* tok_list = (int*)(ws + F_TOK);
  float* wt_list = (float*)(ws + F_WT);
  int* idx2 = (int*)(ws + F_IDX);
  int* counts = (int*)(ws + F_CNT);

  hipMemsetAsync(counts, 0, 64, stream);
  wconv_kernel<<<12288, 256, 0, stream>>>(wg, wu, wd, wgT, wuT, wdT);
  router_kernel<<<T_TOK / 4, 256, 0, stream>>>(x, gate_w, out1, tok_list, wt_list, idx2, counts, xh);
  gemm1_kernel<<<E_NUM * 128 * 8, 256, 0, stream>>>(xh, wgT, wuT, tok_list, counts, hdn);
  gemm2_kernel<<<E_NUM * 128 * 8, 256, 0, stream>>>(hdn, wdT, tok_list, wt_list, counts, y2);
  combine_kernel<<<T_TOK, 256, 0, stream>>>(y2, idx2, counts, out0);
}

// Round 9
// 1382.552 us; speedup vs baseline: 1.0532x; 1.0532x over previous
//
#include <hip/hip_runtime.h>

#define T_TOK 16384
#define H_DIM 2048
#define I_DIM 1024
#define E_NUM 8

// ---- workspace layout (bytes) ----
static const size_t F_WGT = 0;              // wgT [e][I][H] f16, 33554432
static const size_t F_WUT = 33554432ull;    // wuT [e][I][H] f16
static const size_t F_XH  = 67108864ull;    // xh  [T][H] f16, 67108864
static const size_t F_Y2  = 0;              // y2 [32768][H] f16 (overlays wgT/wuT/xh after gemm1)
static const size_t F_WDT = 134217728ull;   // wdT [e][H][I] f16, 33554432
static const size_t F_HDN = 167772160ull;   // hdn [32768][I] f16, 67108864
static const size_t F_TOK = 234881024ull;   // tok_list [E][T] int
static const size_t F_WT  = 235405312ull;   // wt_list  [E][T] f32
static const size_t F_IDX = 235929600ull;   // idx2 [T][2] int (e<<16|pos)
static const size_t F_CNT = 236060672ull;   // counts

typedef float f32x4 __attribute__((ext_vector_type(4)));
typedef _Float16 f16x8 __attribute__((ext_vector_type(8)));
typedef _Float16 f16x4 __attribute__((ext_vector_type(4)));

__device__ __forceinline__ void gload_lds16(const void* g, void* l) {
  __builtin_amdgcn_global_load_lds(
      (const __attribute__((address_space(1))) unsigned int*)g,
      (__attribute__((address_space(3))) unsigned int*)l, 16, 0, 0);
}

// ---------------------------------------------------------------------------
// K0: weight transpose + f32->f16 convert.  in [R][C] f32 -> out [C][R] f16
// ---------------------------------------------------------------------------
__global__ __launch_bounds__(256) void wconv_kernel(
    const float* __restrict__ wg, const float* __restrict__ wu,
    const float* __restrict__ wd, _Float16* __restrict__ wgT,
    _Float16* __restrict__ wuT, _Float16* __restrict__ wdT) {
  const int bx = blockIdx.x;
  const int w = bx >> 12;
  const int r2 = bx & 4095;
  const int e = r2 >> 9;
  const int t = r2 & 511;

  const float* src;
  _Float16* dst;
  int R, C;
  if (w == 0)      { src = wg; dst = wgT; R = H_DIM; C = I_DIM; }
  else if (w == 1) { src = wu; dst = wuT; R = H_DIM; C = I_DIM; }
  else             { src = wd; dst = wdT; R = I_DIM; C = H_DIM; }
  src += (size_t)e * R * C;
  dst += (size_t)e * R * C;

  const int tiles_c = C >> 6;
  const int tr = t / tiles_c;
  const int tc = t % tiles_c;

  __shared__ float tile[64][65];
  const int tid = threadIdx.x;

#pragma unroll
  for (int c = 0; c < 4; ++c) {
    const int q = c * 256 + tid;
    const int row = q >> 4;
    const int col4 = (q & 15) * 4;
    const float4 v = *(const float4*)(src + (size_t)(tr * 64 + row) * C + tc * 64 + col4);
    tile[row][col4 + 0] = v.x;
    tile[row][col4 + 1] = v.y;
    tile[row][col4 + 2] = v.z;
    tile[row][col4 + 3] = v.w;
  }
  __syncthreads();
#pragma unroll
  for (int c = 0; c < 4; ++c) {
    const int q = c * 256 + tid;
    const int row = q >> 4;
    const int col4 = (q & 15) * 4;
    f16x4 o = { (_Float16)tile[col4 + 0][row], (_Float16)tile[col4 + 1][row],
                (_Float16)tile[col4 + 2][row], (_Float16)tile[col4 + 3][row] };
    *(f16x4*)(dst + (size_t)(tc * 64 + row) * R + tr * 64 + col4) = o;
  }
}

// ---------------------------------------------------------------------------
// K1: router.  one wave per token: logits -> out1, top-2 -> expert lists,
// and emits xh (f16 copy of x) since the row is already in registers.
// ---------------------------------------------------------------------------
__global__ __launch_bounds__(256) void router_kernel(
    const float* __restrict__ x, const float* __restrict__ gw,
    float* __restrict__ logits, int* __restrict__ tok_list,
    float* __restrict__ wt_list, int* __restrict__ idx2,
    int* __restrict__ counts, _Float16* __restrict__ xh) {
  const int lane = threadIdx.x & 63;
  const int wave = threadIdx.x >> 6;
  const int t = blockIdx.x * 4 + wave;
  const float* xr = x + (size_t)t * H_DIM;

  float xv[32];
#pragma unroll
  for (int j = 0; j < 32; ++j) xv[j] = xr[lane + j * 64];

  _Float16* xhr = xh + (size_t)t * H_DIM;
#pragma unroll
  for (int j = 0; j < 32; ++j) xhr[lane + j * 64] = (_Float16)xv[j];

  float lg[E_NUM];
#pragma unroll
  for (int e = 0; e < E_NUM; ++e) {
    const float* gr = gw + e * H_DIM;
    float s = 0.f;
#pragma unroll
    for (int j = 0; j < 32; ++j) s += xv[j] * gr[lane + j * 64];
#pragma unroll
    for (int off = 32; off > 0; off >>= 1) s += __shfl_xor(s, off, 64);
    lg[e] = s;
  }

  if (lane == 0) {
#pragma unroll
    for (int e = 0; e < E_NUM; ++e) logits[(size_t)t * E_NUM + e] = lg[e];
    float mx = lg[0];
#pragma unroll
    for (int e = 1; e < E_NUM; ++e) mx = fmaxf(mx, lg[e]);
    float se = 0.f;
#pragma unroll
    for (int e = 0; e < E_NUM; ++e) se += expf(lg[e] - mx);
    int i1 = 0; float b1 = lg[0];
#pragma unroll
    for (int e = 1; e < E_NUM; ++e) { if (lg[e] > b1) { b1 = lg[e]; i1 = e; } }
    int i2 = -1; float b2 = -1e30f;
#pragma unroll
    for (int e = 0; e < E_NUM; ++e) { if (e != i1 && lg[e] > b2) { b2 = lg[e]; i2 = e; } }
    const float p1 = expf(b1 - mx) / se;
    const float p2 = expf(b2 - mx) / se;
    int pos = atomicAdd(&counts[i1], 1);
    tok_list[i1 * T_TOK + pos] = t;
    wt_list[i1 * T_TOK + pos] = p1;
    idx2[t * 2] = (i1 << 16) | pos;
    pos = atomicAdd(&counts[i2], 1);
    tok_list[i2 * T_TOK + pos] = t;
    wt_list[i2 * T_TOK + pos] = p2;
    idx2[t * 2 + 1] = (i2 << 16) | pos;
  }
}

// ---------------------------------------------------------------------------
// K2: grouped GEMM1 (gate+up fused) + SiLU*mul -> hdn.
// r7 structure (proven 470us): 128x128 tile, BK=32, double-buffered 2-phase
// prefetch, combined staging at loop top, XCD swizzle, NO setprio.
// ---------------------------------------------------------------------------
__global__ __launch_bounds__(256) void gemm1_kernel(
    const _Float16* __restrict__ xh, const _Float16* __restrict__ wgT,
    const _Float16* __restrict__ wuT, const int* __restrict__ tok_list,
    const int* __restrict__ counts, _Float16* __restrict__ hdn) {
  const int cpx = (E_NUM * 128 * 8) >> 3;
  int bx = blockIdx.x;
  bx = (bx & 7) * cpx + (bx >> 3);

  const int cb = bx & 7;           // I col block
  const int rb = (bx >> 3) & 127;  // row block (worst case)
  const int e = bx >> 10;
  const int n_e = counts[e];
  const int row0 = rb * 128;
  if (row0 >= n_e) return;
  int goff = 0;
#pragma unroll
  for (int j = 0; j < E_NUM; ++j) goff += (j < e) ? counts[j] : 0;
  const int rem = min(128, n_e - row0);

  __shared__ int toks[128];
  __shared__ __attribute__((aligned(16))) _Float16 As[2][128 * 32];
  __shared__ __attribute__((aligned(16))) _Float16 Bg[2][128 * 32];
  __shared__ __attribute__((aligned(16))) _Float16 Bu[2][128 * 32];

  const int tid = threadIdx.x;
  if (tid < 128) {
    int idx = row0 + tid;
    if (idx > n_e - 1) idx = n_e - 1;
    toks[tid] = tok_list[e * T_TOK + idx];
  }
  __syncthreads();

  const int lane = tid & 63;
  const int wid = tid >> 6;
  const int wr = (wid >> 1) * 64;
  const int wcl = (wid & 1) * 64;
  const int n0 = cb * 128;

  const _Float16* wgTe = wgT + ((size_t)e * I_DIM + n0) * H_DIM;
  const _Float16* wuTe = wuT + ((size_t)e * I_DIM + n0) * H_DIM;

  const _Float16* asrc[2];
  int bofs[2], dofs[2];
#pragma unroll
  for (int c = 0; c < 2; ++c) {
    const int q = c * 256 + tid;
    const int rr = q >> 2;
    const int ch = q & 3;
    const int sch = ch ^ ((rr >> 1) & 3);   // pre-swizzled global source
    asrc[c] = xh + (size_t)toks[rr] * H_DIM + sch * 8;
    bofs[c] = rr * H_DIM + sch * 8;
    dofs[c] = q * 8;                        // linear LDS dest
  }

  const f32x4 z4 = {0.f, 0.f, 0.f, 0.f};
  f32x4 accg[4][4], accu[4][4];
#pragma unroll
  for (int m = 0; m < 4; ++m)
#pragma unroll
    for (int n = 0; n < 4; ++n) { accg[m][n] = z4; accu[m][n] = z4; }

  const int cl = lane & 15;
  const int kq = lane >> 4;

  int aoff[4], boffr[4];
#pragma unroll
  for (int m = 0; m < 4; ++m) {
    const int row = wr + m * 16 + cl;
    aoff[m] = row * 32 + ((kq ^ ((row >> 1) & 3)) * 8);
  }
#pragma unroll
  for (int n = 0; n < 4; ++n) {
    const int row = wcl + n * 16 + cl;
    boffr[n] = row * 32 + ((kq ^ ((row >> 1) & 3)) * 8);
  }

  // prologue: stage k=0 into buf 0, drain, barrier
#pragma unroll
  for (int c = 0; c < 2; ++c) {
    gload_lds16(asrc[c], &As[0][0] + dofs[c]);
    gload_lds16(wgTe + bofs[c], &Bg[0][0] + dofs[c]);
    gload_lds16(wuTe + bofs[c], &Bu[0][0] + dofs[c]);
  }
  asm volatile("s_waitcnt vmcnt(0)" ::: "memory");
  __builtin_amdgcn_s_barrier();
  __builtin_amdgcn_sched_barrier(0);

  const int NK = H_DIM / 32;
  for (int t = 0; t < NK; ++t) {
    const int cur = t & 1;
    if (t + 1 < NK) {
      const int kn = (t + 1) * 32;
#pragma unroll
      for (int c = 0; c < 2; ++c) {
        gload_lds16(asrc[c] + kn, &As[cur ^ 1][0] + dofs[c]);
        gload_lds16(wgTe + bofs[c] + kn, &Bg[cur ^ 1][0] + dofs[c]);
        gload_lds16(wuTe + bofs[c] + kn, &Bu[cur ^ 1][0] + dofs[c]);
      }
    }
    const _Float16* Ac = &As[cur][0];
    const _Float16* Gc = &Bg[cur][0];
    const _Float16* Uc = &Bu[cur][0];
    f16x8 af[4], bg[4], bu[4];
#pragma unroll
    for (int m = 0; m < 4; ++m) af[m] = *(const f16x8*)(Ac + aoff[m]);
#pragma unroll
    for (int n = 0; n < 4; ++n) {
      bg[n] = *(const f16x8*)(Gc + boffr[n]);
      bu[n] = *(const f16x8*)(Uc + boffr[n]);
    }
#pragma unroll
    for (int m = 0; m < 4; ++m)
#pragma unroll
      for (int n = 0; n < 4; ++n) {
        accg[m][n] = __builtin_amdgcn_mfma_f32_16x16x32_f16(af[m], bg[n], accg[m][n], 0, 0, 0);
        accu[m][n] = __builtin_amdgcn_mfma_f32_16x16x32_f16(af[m], bu[n], accu[m][n], 0, 0, 0);
      }
    asm volatile("s_waitcnt vmcnt(0)" ::: "memory");
    __builtin_amdgcn_s_barrier();
    __builtin_amdgcn_sched_barrier(0);
  }

  const int rq = lane >> 4;
#pragma unroll
  for (int m = 0; m < 4; ++m) {
#pragma unroll
    for (int r = 0; r < 4; ++r) {
      const int row = wr + m * 16 + rq * 4 + r;
      if (row < rem) {
        const size_t grow = (size_t)(goff + row0 + row);
#pragma unroll
        for (int n = 0; n < 4; ++n) {
          const float g = accg[m][n][r];
          const float u = accu[m][n][r];
          const float h = g / (1.f + __expf(-g)) * u;
          hdn[grow * I_DIM + n0 + wcl + n * 16 + cl] = (_Float16)h;
        }
      }
    }
  }
}

// ---------------------------------------------------------------------------
// K3: grouped GEMM2 (down proj) -> weight-scaled compacted y2 (f16).
// 128x256 tile, 8 waves (512 thr), wave-tile 64x64 -> acc[4][4] (=gemm1's
// VGPR shape, 4 waves/SIMD).  Halves barrier-interval count vs 128x128 while
// keeping occupancy.  BK=32 dbuf 2-phase, swizzle, XCD swizzle, no setprio.
// ---------------------------------------------------------------------------
__global__ __launch_bounds__(512) void gemm2_kernel(
    const _Float16* __restrict__ hdn, const _Float16* __restrict__ wdT,
    const int* __restrict__ tok_list, const float* __restrict__ wt_list,
    const int* __restrict__ counts, _Float16* __restrict__ y2) {
  const int cpx = (E_NUM * 128 * 8) >> 3;
  int bx = blockIdx.x;
  bx = (bx & 7) * cpx + (bx >> 3);

  const int nb = bx & 7;           // H col block (256 wide)
  const int rb = (bx >> 3) & 127;  // row block of 128
  const int e = bx >> 10;
  const int n_e = counts[e];
  const int row0 = rb * 128;
  if (row0 >= n_e) return;
  int goff = 0;
#pragma unroll
  for (int j = 0; j < E_NUM; ++j) goff += (j < e) ? counts[j] : 0;
  const int rem = min(128, n_e - row0);

  __shared__ float wts[128];
  __shared__ __attribute__((aligned(16))) _Float16 As[2][128 * 32];
  __shared__ __attribute__((aligned(16))) _Float16 Bs[2][256 * 32];

  const int tid = threadIdx.x;
  if (tid < 128) {
    int idx = row0 + tid;
    const bool valid = (idx < n_e);
    wts[tid] = valid ? wt_list[e * T_TOK + min(idx, n_e - 1)] : 0.f;
  }
  __syncthreads();

  const int lane = tid & 63;
  const int wid = tid >> 6;          // 0..7
  const int wr = (wid >> 2) * 64;    // {0, 64}
  const int wcl = (wid & 3) * 64;    // {0, 64, 128, 192}
  const int h0 = nb * 256;

  const _Float16* wdTe = wdT + ((size_t)e * H_DIM + h0) * I_DIM;
  const _Float16* hdnb = hdn + (size_t)(goff + row0) * I_DIM;

  // staging: A = 512 chunks (1/thread), B = 1024 chunks (2/thread)
  const _Float16* asrc;
  int adof;
  {
    const int q = tid;
    const int rr = q >> 2;
    const int ch = q & 3;
    const int sch = ch ^ ((rr >> 1) & 3);
    const int rrc = min(rr, rem - 1);       // clamp source row only
    asrc = hdnb + (size_t)rrc * I_DIM + sch * 8;
    adof = q * 8;
  }
  int bofs[2], bdofs[2];
#pragma unroll
  for (int c = 0; c < 2; ++c) {
    const int q = c * 512 + tid;
    const int rr = q >> 2;                  // 0..255
    const int ch = q & 3;
    const int sch = ch ^ ((rr >> 1) & 3);
    bofs[c] = rr * I_DIM + sch * 8;
    bdofs[c] = q * 8;
  }

  const f32x4 z4 = {0.f, 0.f, 0.f, 0.f};
  f32x4 acc[4][4];
#pragma unroll
  for (int m = 0; m < 4; ++m)
#pragma unroll
    for (int n = 0; n < 4; ++n) acc[m][n] = z4;

  const int cl = lane & 15;
  const int kq = lane >> 4;

  int aoff[4], boffr[4];
#pragma unroll
  for (int m = 0; m < 4; ++m) {
    const int row = wr + m * 16 + cl;
    aoff[m] = row * 32 + ((kq ^ ((row >> 1) & 3)) * 8);
  }
#pragma unroll
  for (int n = 0; n < 4; ++n) {
    const int row = wcl + n * 16 + cl;
    boffr[n] = row * 32 + ((kq ^ ((row >> 1) & 3)) * 8);
  }

  // prologue
  gload_lds16(asrc, &As[0][0] + adof);
#pragma unroll
  for (int c = 0; c < 2; ++c) gload_lds16(wdTe + bofs[c], &Bs[0][0] + bdofs[c]);
  asm volatile("s_waitcnt vmcnt(0)" ::: "memory");
  __builtin_amdgcn_s_barrier();
  __builtin_amdgcn_sched_barrier(0);

  const int NK = I_DIM / 32;
  for (int t = 0; t < NK; ++t) {
    const int cur = t & 1;
    if (t + 1 < NK) {
      const int kn = (t + 1) * 32;
      gload_lds16(asrc + kn, &As[cur ^ 1][0] + adof);
#pragma unroll
      for (int c = 0; c < 2; ++c) gload_lds16(wdTe + bofs[c] + kn, &Bs[cur ^ 1][0] + bdofs[c]);
    }
    const _Float16* Ac = &As[cur][0];
    const _Float16* Bc = &Bs[cur][0];
    f16x8 af[4], bf[4];
#pragma unroll
    for (int m = 0; m < 4; ++m) af[m] = *(const f16x8*)(Ac + aoff[m]);
#pragma unroll
    for (int n = 0; n < 4; ++n) bf[n] = *(const f16x8*)(Bc + boffr[n]);
#pragma unroll
    for (int m = 0; m < 4; ++m)
#pragma unroll
      for (int n = 0; n < 4; ++n)
        acc[m][n] = __builtin_amdgcn_mfma_f32_16x16x32_f16(af[m], bf[n], acc[m][n], 0, 0, 0);
    asm volatile("s_waitcnt vmcnt(0)" ::: "memory");
    __builtin_amdgcn_s_barrier();
    __builtin_amdgcn_sched_barrier(0);
  }

  const int rq = lane >> 4;
#pragma unroll
  for (int m = 0; m < 4; ++m) {
#pragma unroll
    for (int r = 0; r < 4; ++r) {
      const int row = wr + m * 16 + rq * 4 + r;
      if (row < rem) {
        const float w = wts[row];
        _Float16* yrow = y2 + (size_t)(goff + row0 + row) * H_DIM + h0 + wcl;
#pragma unroll
        for (int n = 0; n < 4; ++n)
          yrow[n * 16 + cl] = (_Float16)(acc[m][n][r] * w);
      }
    }
  }
}

// ---------------------------------------------------------------------------
// K4: combine — out0[t] = y2[slot0(t)] + y2[slot1(t)]
// ---------------------------------------------------------------------------
__global__ __launch_bounds__(256) void combine_kernel(
    const _Float16* __restrict__ y2, const int* __restrict__ idx2,
    const int* __restrict__ counts, float* __restrict__ out) {
  const int t = blockIdx.x;
  int pref[E_NUM];
  int run = 0;
#pragma unroll
  for (int e = 0; e < E_NUM; ++e) { pref[e] = run; run += counts[e]; }
  const int p0 = idx2[t * 2];
  const int p1 = idx2[t * 2 + 1];
  const size_t r0 = (size_t)(pref[p0 >> 16] + (p0 & 0xFFFF)) * H_DIM;
  const size_t r1 = (size_t)(pref[p1 >> 16] + (p1 & 0xFFFF)) * H_DIM;
  const int o = threadIdx.x * 8;
  const f16x8 a = *(const f16x8*)(y2 + r0 + o);
  const f16x8 b = *(const f16x8*)(y2 + r1 + o);
  float* orow = out + (size_t)t * H_DIM + o;
  float4 lo = { (float)a[0] + (float)b[0], (float)a[1] + (float)b[1],
                (float)a[2] + (float)b[2], (float)a[3] + (float)b[3] };
  float4 hi = { (float)a[4] + (float)b[4], (float)a[5] + (float)b[5],
                (float)a[6] + (float)b[6], (float)a[7] + (float)b[7] };
  *(float4*)orow = lo;
  *(float4*)(orow + 4) = hi;
}

// ---------------------------------------------------------------------------
extern "C" void kernel_launch(void* const* d_in, const int* in_sizes, int n_in,
                              void* d_out, int out_size, void* d_ws, size_t ws_size,
                              hipStream_t stream) {
  (void)in_sizes; (void)n_in; (void)out_size; (void)ws_size;
  const float* x      = (const float*)d_in[0];
  const float* gate_w = (const float*)d_in[1];
  const float* wg     = (const float*)d_in[2];
  const float* wu     = (const float*)d_in[3];
  const float* wd     = (const float*)d_in[4];
  float* out0 = (float*)d_out;
  float* out1 = out0 + (size_t)T_TOK * H_DIM;

  char* ws = (char*)d_ws;
  _Float16* wgT = (_Float16*)(ws + F_WGT);
  _Float16* wuT = (_Float16*)(ws + F_WUT);
  _Float16* xh  = (_Float16*)(ws + F_XH);
  _Float16* y2  = (_Float16*)(ws + F_Y2);
  _Float16* wdT = (_Float16*)(ws + F_WDT);
  _Float16* hdn = (_Float16*)(ws + F_HDN);
  int* tok_list = (int*)(ws + F_TOK);
  float* wt_list = (float*)(ws + F_WT);
  int* idx2 = (int*)(ws + F_IDX);
  int* counts = (int*)(ws + F_CNT);

  hipMemsetAsync(counts, 0, 64, stream);
  wconv_kernel<<<12288, 256, 0, stream>>>(wg, wu, wd, wgT, wuT, wdT);
  router_kernel<<<T_TOK / 4, 256, 0, stream>>>(x, gate_w, out1, tok_list, wt_list, idx2, counts, xh);
  gemm1_kernel<<<E_NUM * 128 * 8, 256, 0, stream>>>(xh, wgT, wuT, tok_list, counts, hdn);
  gemm2_kernel<<<E_NUM * 128 * 8, 512, 0, stream>>>(hdn, wdT, tok_list, wt_list, counts, y2);
  combine_kernel<<<T_TOK, 256, 0, stream>>>(y2, idx2, counts, out0);
}